// Round 6
// baseline (466.093 us; speedup 1.0000x reference)
//
#include <hip/hip_runtime.h>
#include <hip/hip_bf16.h>
#include <math.h>

// RelationAwareTreeLSTMCell on gfx950 — fp32 in/out.
// B=4096 N=32 H=256 DIN=256 R=3.
// Round 9: flip the design point. Evidence: LDS pool ~112 KB/CU caps NBC=2 at
//   2 blocks/CU (16 thin waves, 64 regs) and every pipe idles ~86% — latency
//   bound with no room to deepen. New point: 1 block/CU, 8 FAT waves:
//   - waves_per_eu(2,2): 256-VGPR budget -> deep load queues, zero spills
//     (round-1's prefetch failed at 64-reg budget, not on principle).
//   - LDS double-buffered chs + T14 pipeline: chunk k+1 child_h and chunk k
//     child_c issued to regs BEFORE the GEMM, consumed after (~64 held regs).
//     One barrier per chunk; loads complete under GEMM, barrier drain is cheap.
//   - MB=16 (grid 256 = 1 block/CU exactly): gate-weight demand halves
//     (393->197 MB; W_f demand is NBC-invariant). Total 1180->983 MB.
// fused_main: 256 blocks x 512 thr, 8 chunks of NBC=2 batches, dbuf LDS ~99 KB.
//   Per chunk: [issue h(ck+1)] -> softmax(ck) -> [issue cc(ck)] -> hsum(ck) ->
//   rid-masked MFMA GEMM(ck) -> cs epilogue(ck) -> dot+cvt+write h(ck+1) ->
//   barrier. Then gate GEMM (16 x 512)@(512 x 768) + fused epilogue (r0 form).

#define B_    4096
#define N_    32
#define H_    256
#define DIN_  256
#define R_    3
#define MB    16
#define NBC   2
#define CHUNKS (MB / NBC)
#define DECAY 0.7f

// ws layout (bf16 elements)
#define WS_WF   0
#define WS_WI   196608
#define WS_WO   327680
#define WS_WU   458752
#define WS_ELEMS 589824                       // * 2 B = 1,179,648 B needed

typedef __bf16 bf16;
typedef bf16  bf16x8 __attribute__((ext_vector_type(8)));
typedef float f32x4  __attribute__((ext_vector_type(4)));

__device__ __forceinline__ float sigmoidf_(float x) { return 1.0f / (1.0f + __expf(-x)); }

__device__ __forceinline__ bf16x8 cvt8_nt(const float* p) {
    f32x4 a = __builtin_nontemporal_load((const f32x4*)p);
    f32x4 b = __builtin_nontemporal_load((const f32x4*)(p + 4));
    bf16x8 r;
    #pragma unroll
    for (int j = 0; j < 4; ++j) { r[j] = (bf16)a[j]; r[j + 4] = (bf16)b[j]; }
    return r;
}
__device__ __forceinline__ bf16x8 cvt8_c(const float* p) {
    f32x4 a = *(const f32x4*)p;
    f32x4 b = *(const f32x4*)(p + 4);
    bf16x8 r;
    #pragma unroll
    for (int j = 0; j < 4; ++j) { r[j] = (bf16)a[j]; r[j + 4] = (bf16)b[j]; }
    return r;
}

template<bool WSW>
__device__ __forceinline__ bf16x8 ldw8(const bf16* wsp, const float* fp, int idx) {
    if constexpr (WSW) return *(const bf16x8*)(wsp + idx);
    else               return cvt8_c(fp + idx);
}

// ---- weight prep: fp32 -> bf16 into d_ws. 288 blocks x 256 thr, exact cover. ----
__global__ __launch_bounds__(256) void wprep(
    const float* __restrict__ Wf, const float* __restrict__ Wi,
    const float* __restrict__ Wo, const float* __restrict__ Wu,
    bf16* __restrict__ ws)
{
    int i = (blockIdx.x * 256 + threadIdx.x) * 8;
    const float* src; int off;
    if      (i < WS_WI) { src = Wf; off = i - WS_WF; }
    else if (i < WS_WO) { src = Wi; off = i - WS_WI; }
    else if (i < WS_WU) { src = Wo; off = i - WS_WO; }
    else                { src = Wu; off = i - WS_WU; }
    *(bf16x8*)(ws + i) = cvt8_c(src + off);
}

template<bool WSW>
__global__ __launch_bounds__(512) __attribute__((amdgpu_waves_per_eu(2, 2)))
void fused_main(
    const float* __restrict__ ivec,
    const float* __restrict__ child_h, const float* __restrict__ child_c,
    const int*  __restrict__ rel_ids,  const void* __restrict__ vmaskp,
    const float* __restrict__ rel_emb,
    const float* __restrict__ W_i, const float* __restrict__ b_i,
    const float* __restrict__ W_f, const float* __restrict__ b_f,
    const float* __restrict__ W_o, const float* __restrict__ b_o,
    const float* __restrict__ W_u, const float* __restrict__ b_u,
    const float* __restrict__ w_att, const float* __restrict__ b_att,
    const bf16* __restrict__ ws, float* __restrict__ out)
{
    __shared__ __align__(16) bf16 chs[2][NBC][N_][264];  // 67584 B (dbuf)
    __shared__ __align__(16) bf16 hsumL[MB][264];        //  8448 B
    __shared__ float csL[MB][H_];                        // 16384 B
    __shared__ float watt[H_];                           //  1024 B
    __shared__ float bfl[R_][H_];                        //  3072 B
    __shared__ float dall[MB][N_];                       //  2048 B
    __shared__ int   rids[MB][N_];                       //  2048 B
    __shared__ float scoreS[2][NBC * N_];                //   512 B
    __shared__ float rdotL[4];
    __shared__ int   m8flag;

    const int tid  = threadIdx.x;
    const int wave = tid >> 6;
    const int lane = tid & 63;
    const int t    = lane & 15;
    const int q    = lane >> 4;
    const int b0   = blockIdx.x * MB;

    const bf16* wfb = ws + WS_WF;
    const bf16* wib = ws + WS_WI;
    const bf16* wob = ws + WS_WO;
    const bf16* wub = ws + WS_WU;

    // ---- mask-format probe (wave 0): byte-bools have nonzero "upper bytes" ----
    if (tid < 64) {
        const unsigned char* vb = (const unsigned char*)vmaskp;
        int bad = vb[tid * 4 + 1] | vb[tid * 4 + 2] | vb[tid * 4 + 3];
        unsigned long long any = __ballot(bad != 0);
        if (tid == 0) m8flag = (any != 0ull) ? 1 : 0;
    }
    __syncthreads();

    // ---- small tables ----
    if (tid < H_) watt[tid] = w_att[tid];
    {
        int idx = b0 * N_ + tid;           // MB*N_ == 512 == blockDim
        rids[tid >> 5][tid & 31] = rel_ids[idx];
        bool vm = m8flag ? (((const unsigned char*)vmaskp)[idx] != 0)
                         : (((const int*)vmaskp)[idx] != 0);
        dall[tid >> 5][tid & 31] = vm ? DECAY : 1.0f;
    }
    for (int i = tid; i < R_ * H_; i += 512) ((float*)bfl)[i] = b_f[i];
    if (tid == 0) rdotL[3] = b_att[0];
    __syncthreads();

    // rdot[r] = dot(rel_emb[r], w_att); published by the prologue barrier
    if (wave < R_) {
        int r = wave;
        float p = 0.f;
        #pragma unroll
        for (int j = 0; j < 4; ++j) {
            int h = lane * 4 + j;
            p += rel_emb[r * H_ + h] * watt[h];
        }
        #pragma unroll
        for (int off = 32; off >= 1; off >>= 1) p += __shfl_xor(p, off);
        if (lane == 0) rdotL[r] = p;
    }

    // ---- prologue: load + dot + stage chunk 0 into chs[0] ----
    {
        size_t base = (size_t)b0 * (N_ * H_);
        float dp[4];
        #pragma unroll
        for (int it = 0; it < 4; ++it) {
            int ge = (it * 512 + tid) << 3;          // 0..16376
            int row = ge >> 8, h = ge & 255;
            f32x4 a = __builtin_nontemporal_load((const f32x4*)(child_h + base + ge));
            f32x4 b = __builtin_nontemporal_load((const f32x4*)(child_h + base + ge + 4));
            bf16x8 r; float p = 0.f;
            #pragma unroll
            for (int j = 0; j < 4; ++j) {
                r[j] = (bf16)a[j]; r[j + 4] = (bf16)b[j];
                p += a[j] * watt[h + j] + b[j] * watt[h + 4 + j];
            }
            *(bf16x8*)(&chs[0][row >> 5][row & 31][h]) = r;
            dp[it] = p;
        }
        #pragma unroll
        for (int off = 16; off >= 1; off >>= 1) {
            dp[0] += __shfl_xor(dp[0], off);
            dp[1] += __shfl_xor(dp[1], off);
            dp[2] += __shfl_xor(dp[2], off);
            dp[3] += __shfl_xor(dp[3], off);
        }
        if ((tid & 31) == 0) {
            int grp = tid >> 5;
            #pragma unroll
            for (int it = 0; it < 4; ++it) scoreS[0][it * 16 + grp] = dp[it];
        }
    }
    __syncthreads();

    // ================= chunk loop: NBC=2 batches each, dbuf pipeline ========
    for (int ck = 0; ck < CHUNKS; ++ck) {
        const int cur = ck & 1, nxt = cur ^ 1;

        // ---- (1) issue next chunk's child_h loads early (T14) ----
        f32x4 hA[4], hB[4];
        if (ck + 1 < CHUNKS) {
            size_t base = (size_t)(b0 + (ck + 1) * NBC) * (N_ * H_);
            #pragma unroll
            for (int it = 0; it < 4; ++it) {
                int ge = (it * 512 + tid) << 3;
                hA[it] = __builtin_nontemporal_load((const f32x4*)(child_h + base + ge));
                hB[it] = __builtin_nontemporal_load((const f32x4*)(child_h + base + ge + 4));
            }
        }

        // ---- (2) per-wave softmax (redundant across waves, in regs) ----
        float att;      // attn * decay for this lane's (bi=lane>>5, n=lane&31)
        {
            int bi = lane >> 5, n = lane & 31;
            int bl = ck * NBC + bi;
            float d = dall[bl][n];
            float s = d * scoreS[cur][lane] + rdotL[rids[bl][n]] + rdotL[3];
            float m = s;
            #pragma unroll
            for (int off = 16; off >= 1; off >>= 1) m = fmaxf(m, __shfl_xor(m, off));
            float e = __expf(s - m);
            float sum = e;
            #pragma unroll
            for (int off = 16; off >= 1; off >>= 1) sum += __shfl_xor(sum, off);
            att = (e / sum) * d;
        }

        // ---- (3) issue this chunk's child_c loads early (T14) ----
        f32x4 cc[2][2][2];   // [m2][bi][j]
        #pragma unroll
        for (int m2 = 0; m2 < 2; ++m2)
            #pragma unroll
            for (int bi = 0; bi < NBC; ++bi) {
                size_t cbase = (size_t)(b0 + ck * NBC + bi) * (N_ * H_);
                #pragma unroll
                for (int j = 0; j < 2; ++j)
                    cc[m2][bi][j] = __builtin_nontemporal_load(
                        (const f32x4*)(child_c + cbase + (size_t)(((j << 4) + t)) * H_
                                       + (wave * 2 + m2) * 16 + q * 4));
            }

        // ---- (4) h_sum -> LDS (attn via shfl broadcast) ----
        {
            int bi = tid >> 8, g = tid & 255;
            int bl = ck * NBC + bi;
            float s = 0.f;
            #pragma unroll 8
            for (int n = 0; n < N_; ++n) {
                float av = __shfl(att, (bi << 5) | n);
                s += av * (float)chs[cur][bi][n][g];
            }
            hsumL[bl][g] = (bf16)s;
        }

        // ---- (5) rid-masked MFMA GEMM: Q[g,n] (M=256, N=64, K=3x256) ----
        f32x4 acc[2][4];
        #pragma unroll
        for (int i = 0; i < 2; ++i)
            #pragma unroll
            for (int j = 0; j < 4; ++j)
                #pragma unroll
                for (int c = 0; c < 4; ++c) acc[i][j][c] = 0.0f;

        bf16x8 bzero;
        #pragma unroll
        for (int i = 0; i < 8; ++i) bzero[i] = (bf16)0.0f;

        int myrid[4];
        #pragma unroll
        for (int nt = 0; nt < 4; ++nt)
            myrid[nt] = rids[ck * NBC + (nt >> 1)][((nt & 1) << 4) + t];

        #pragma unroll
        for (int kc = 0; kc < 8; ++kc) {
            const int k = kc * 32 + q * 8;
            bf16x8 v[4];
            #pragma unroll
            for (int nt = 0; nt < 4; ++nt)
                v[nt] = *(const bf16x8*)(&chs[cur][nt >> 1][((nt & 1) << 4) + t][k]);
            #pragma unroll
            for (int r = 0; r < R_; ++r) {
                bf16x8 afrag[2];
                #pragma unroll
                for (int m2 = 0; m2 < 2; ++m2) {
                    int g = (wave * 2 + m2) * 16 + t;
                    afrag[m2] = ldw8<WSW>(wfb, W_f, (r * H_ + g) * H_ + k);
                }
                #pragma unroll
                for (int nt = 0; nt < 4; ++nt) {
                    bf16x8 vm = (myrid[nt] == r) ? v[nt] : bzero;
                    acc[0][nt] = __builtin_amdgcn_mfma_f32_16x16x32_bf16(afrag[0], vm, acc[0][nt], 0, 0, 0);
                    acc[1][nt] = __builtin_amdgcn_mfma_f32_16x16x32_bf16(afrag[1], vm, acc[1][nt], 0, 0, 0);
                }
            }
        }

        // ---- (6) cs epilogue: consume prefetched cc ----
        #pragma unroll
        for (int m2 = 0; m2 < 2; ++m2) {
            #pragma unroll
            for (int reg = 0; reg < 4; ++reg) {
                const int g = (wave * 2 + m2) * 16 + q * 4 + reg;
                #pragma unroll
                for (int bi = 0; bi < NBC; ++bi) {
                    int bl = ck * NBC + bi;
                    float p = 0.f;
                    #pragma unroll
                    for (int j = 0; j < 2; ++j) {
                        int nt = bi * 2 + j;
                        int n  = (j << 4) + t;
                        float d = dall[bl][n];
                        p += cc[m2][bi][j][reg] * d
                             * fmaf(d, acc[m2][nt][reg], bfl[rids[bl][n]][g]);
                    }
                    p += __shfl_xor(p, 1);
                    p += __shfl_xor(p, 2);
                    p += __shfl_xor(p, 4);
                    p += __shfl_xor(p, 8);
                    if (t == 0) csL[bl][g] = p;
                }
            }
        }

        // ---- (7) dot + cvt + stage next chunk into chs[nxt] ----
        if (ck + 1 < CHUNKS) {
            float dp[4];
            #pragma unroll
            for (int it = 0; it < 4; ++it) {
                int ge = (it * 512 + tid) << 3;
                int row = ge >> 8, h = ge & 255;
                bf16x8 r; float p = 0.f;
                #pragma unroll
                for (int j = 0; j < 4; ++j) {
                    r[j] = (bf16)hA[it][j]; r[j + 4] = (bf16)hB[it][j];
                    p += hA[it][j] * watt[h + j] + hB[it][j] * watt[h + 4 + j];
                }
                *(bf16x8*)(&chs[nxt][row >> 5][row & 31][h]) = r;
                dp[it] = p;
            }
            #pragma unroll
            for (int off = 16; off >= 1; off >>= 1) {
                dp[0] += __shfl_xor(dp[0], off);
                dp[1] += __shfl_xor(dp[1], off);
                dp[2] += __shfl_xor(dp[2], off);
                dp[3] += __shfl_xor(dp[3], off);
            }
            if ((tid & 31) == 0) {
                int grp = tid >> 5;
                #pragma unroll
                for (int it = 0; it < 4; ++it) scoreS[nxt][it * 16 + grp] = dp[it];
            }
        }
        __syncthreads();
    }

    // ============ gates: (16 x 512) @ (512 x 768), fused epilogue ============
    const int j0 = wave * 32;
    f32x4 accI[2], accO[2], accU[2];
    #pragma unroll
    for (int c = 0; c < 2; ++c)
        #pragma unroll
        for (int r = 0; r < 4; ++r) { accI[c][r] = 0.f; accO[c][r] = 0.f; accU[c][r] = 0.f; }

    #pragma unroll
    for (int kc = 0; kc < 16; ++kc) {
        const int k = kc * 32 + q * 8;
        bf16x8 a;
        if (kc < 8) a = cvt8_nt(ivec + (size_t)(b0 + t) * DIN_ + k);
        else        a = *(const bf16x8*)(&hsumL[t][k - 256]);
        #pragma unroll
        for (int c = 0; c < 2; ++c) {
            int j = j0 + c * 16 + t;
            bf16x8 bI = ldw8<WSW>(wib, W_i, j * 512 + k);
            bf16x8 bO = ldw8<WSW>(wob, W_o, j * 512 + k);
            bf16x8 bU = ldw8<WSW>(wub, W_u, j * 512 + k);
            accI[c] = __builtin_amdgcn_mfma_f32_16x16x32_bf16(a, bI, accI[c], 0, 0, 0);
            accO[c] = __builtin_amdgcn_mfma_f32_16x16x32_bf16(a, bO, accO[c], 0, 0, 0);
            accU[c] = __builtin_amdgcn_mfma_f32_16x16x32_bf16(a, bU, accU[c], 0, 0, 0);
        }
    }

    #pragma unroll
    for (int c = 0; c < 2; ++c) {
        const int j = j0 + c * 16 + t;
        float biv = b_i[j], bov = b_o[j], buv = b_u[j];
        #pragma unroll
        for (int reg = 0; reg < 4; ++reg) {
            int bl = q * 4 + reg;
            size_t o1 = (size_t)(b0 + bl) * H_ + j;
            size_t o2 = (size_t)B_ * H_ + o1;
            float iv = sigmoidf_(accI[c][reg] + biv);
            float ov = sigmoidf_(accO[c][reg] + bov);
            float uv = tanhf(accU[c][reg] + buv);
            float cv = fmaf(iv, uv, csL[bl][j]);
            float hv = ov * tanhf(cv);
            __builtin_nontemporal_store(hv, out + o1);
            __builtin_nontemporal_store(cv, out + o2);
        }
    }
}

extern "C" void kernel_launch(void* const* d_in, const int* in_sizes, int n_in,
                              void* d_out, int out_size, void* d_ws, size_t ws_size,
                              hipStream_t stream)
{
    const float* ivec    = (const float*)d_in[0];
    const float* child_h = (const float*)d_in[1];
    const float* child_c = (const float*)d_in[2];
    const int*   relids  = (const int*)d_in[3];
    const void*  vmask   = d_in[4];
    const float* rel_emb = (const float*)d_in[5];
    const float* W_i     = (const float*)d_in[6];
    const float* b_i     = (const float*)d_in[7];
    const float* W_f     = (const float*)d_in[8];
    const float* b_f     = (const float*)d_in[9];
    const float* W_o     = (const float*)d_in[10];
    const float* b_o     = (const float*)d_in[11];
    const float* W_u     = (const float*)d_in[12];
    const float* b_u     = (const float*)d_in[13];
    const float* w_att   = (const float*)d_in[14];
    const float* b_att   = (const float*)d_in[15];
    float* out = (float*)d_out;
    bf16*  ws  = (bf16*)d_ws;

    const bool wsw = (ws_size >= (size_t)WS_ELEMS * sizeof(bf16));

    if (wsw) {
        hipLaunchKernelGGL(wprep, dim3(WS_ELEMS / 8 / 256), dim3(256), 0, stream,
                           W_f, W_i, W_o, W_u, ws);
        hipLaunchKernelGGL((fused_main<true>), dim3(B_ / MB), dim3(512), 0, stream,
                           ivec, child_h, child_c, relids, vmask, rel_emb,
                           W_i, b_i, W_f, b_f, W_o, b_o, W_u, b_u, w_att, b_att,
                           ws, out);
    } else {
        hipLaunchKernelGGL((fused_main<false>), dim3(B_ / MB), dim3(512), 0, stream,
                           ivec, child_h, child_c, relids, vmask, rel_emb,
                           W_i, b_i, W_f, b_f, W_o, b_o, W_u, b_u, w_att, b_att,
                           ws, out);
    }
}

// Round 7
// 424.898 us; speedup vs baseline: 1.0970x; 1.0970x over previous
//
#include <hip/hip_runtime.h>
#include <hip/hip_bf16.h>
#include <math.h>

// RelationAwareTreeLSTMCell on gfx950 — fp32 in/out.
// B=4096 N=32 H=256 DIN=256 R=3.
// Round 10: halve the W_f streaming passes (the cross-round invariant that
//   tracks dur). NBC=4 per chunk: 4 chunks instead of 8 -> W_f L2-load count
//   786K -> 393K per dispatch, and 16 MFMAs per weight-fragment pair (was 8)
//   to hide each dependent L2 load. Pipeline frills from r9 dropped (staging
//   stalls measured ~3 us/block — noise). Single-buffer chs[4][32][264].
// fused_main: 256 blocks x 512 thr, waves_per_eu(2,2) (256-VGPR budget),
//   4 chunks of NBC=4 batches, LDS ~101 KB, 1 block/CU.
//   Per chunk: barrier -> stage child_h (fused attn dot) -> barrier ->
//   per-wave softmax (2 pairs/lane) -> hsum (2 passes, shfl attn) ->
//   rid-masked MFMA GEMM (M=256,N=128,K=3x256) -> direct-cc epilogue.
//   Then gate GEMM (16 x 512)@(512 x 768) + fused sigmoid/tanh -> fp32 out.

#define B_    4096
#define N_    32
#define H_    256
#define DIN_  256
#define R_    3
#define MB    16
#define NBC   4
#define CHUNKS (MB / NBC)
#define DECAY 0.7f

// ws layout (bf16 elements)
#define WS_WF   0
#define WS_WI   196608
#define WS_WO   327680
#define WS_WU   458752
#define WS_ELEMS 589824                       // * 2 B = 1,179,648 B needed

typedef __bf16 bf16;
typedef bf16  bf16x8 __attribute__((ext_vector_type(8)));
typedef float f32x4  __attribute__((ext_vector_type(4)));

__device__ __forceinline__ float sigmoidf_(float x) { return 1.0f / (1.0f + __expf(-x)); }

__device__ __forceinline__ bf16x8 cvt8_nt(const float* p) {
    f32x4 a = __builtin_nontemporal_load((const f32x4*)p);
    f32x4 b = __builtin_nontemporal_load((const f32x4*)(p + 4));
    bf16x8 r;
    #pragma unroll
    for (int j = 0; j < 4; ++j) { r[j] = (bf16)a[j]; r[j + 4] = (bf16)b[j]; }
    return r;
}
__device__ __forceinline__ bf16x8 cvt8_c(const float* p) {
    f32x4 a = *(const f32x4*)p;
    f32x4 b = *(const f32x4*)(p + 4);
    bf16x8 r;
    #pragma unroll
    for (int j = 0; j < 4; ++j) { r[j] = (bf16)a[j]; r[j + 4] = (bf16)b[j]; }
    return r;
}

template<bool WSW>
__device__ __forceinline__ bf16x8 ldw8(const bf16* wsp, const float* fp, int idx) {
    if constexpr (WSW) return *(const bf16x8*)(wsp + idx);
    else               return cvt8_c(fp + idx);
}

// ---- weight prep: fp32 -> bf16 into d_ws. 288 blocks x 256 thr, exact cover. ----
__global__ __launch_bounds__(256) void wprep(
    const float* __restrict__ Wf, const float* __restrict__ Wi,
    const float* __restrict__ Wo, const float* __restrict__ Wu,
    bf16* __restrict__ ws)
{
    int i = (blockIdx.x * 256 + threadIdx.x) * 8;
    const float* src; int off;
    if      (i < WS_WI) { src = Wf; off = i - WS_WF; }
    else if (i < WS_WO) { src = Wi; off = i - WS_WI; }
    else if (i < WS_WU) { src = Wo; off = i - WS_WO; }
    else                { src = Wu; off = i - WS_WU; }
    *(bf16x8*)(ws + i) = cvt8_c(src + off);
}

template<bool WSW>
__global__ __launch_bounds__(512) __attribute__((amdgpu_waves_per_eu(2, 2)))
void fused_main(
    const float* __restrict__ ivec,
    const float* __restrict__ child_h, const float* __restrict__ child_c,
    const int*  __restrict__ rel_ids,  const void* __restrict__ vmaskp,
    const float* __restrict__ rel_emb,
    const float* __restrict__ W_i, const float* __restrict__ b_i,
    const float* __restrict__ W_f, const float* __restrict__ b_f,
    const float* __restrict__ W_o, const float* __restrict__ b_o,
    const float* __restrict__ W_u, const float* __restrict__ b_u,
    const float* __restrict__ w_att, const float* __restrict__ b_att,
    const bf16* __restrict__ ws, float* __restrict__ out)
{
    __shared__ __align__(16) bf16 chs[NBC][N_][264];   // 67584 B
    __shared__ __align__(16) bf16 hsumL[MB][264];      //  8448 B
    __shared__ float csL[MB][H_];                      // 16384 B
    __shared__ float watt[H_];                         //  1024 B
    __shared__ float bfl[R_][H_];                      //  3072 B
    __shared__ float dall[MB][N_];                     //  2048 B
    __shared__ int   rids[MB][N_];                     //  2048 B
    __shared__ float scoreT[NBC * N_];                 //   512 B
    __shared__ float rdotL[4];
    __shared__ int   m8flag;

    const int tid  = threadIdx.x;
    const int wave = tid >> 6;
    const int lane = tid & 63;
    const int t    = lane & 15;
    const int q    = lane >> 4;
    const int b0   = blockIdx.x * MB;

    const bf16* wfb = ws + WS_WF;
    const bf16* wib = ws + WS_WI;
    const bf16* wob = ws + WS_WO;
    const bf16* wub = ws + WS_WU;

    // ---- mask-format probe (wave 0): byte-bools have nonzero "upper bytes" ----
    if (tid < 64) {
        const unsigned char* vb = (const unsigned char*)vmaskp;
        int bad = vb[tid * 4 + 1] | vb[tid * 4 + 2] | vb[tid * 4 + 3];
        unsigned long long any = __ballot(bad != 0);
        if (tid == 0) m8flag = (any != 0ull) ? 1 : 0;
    }
    __syncthreads();

    // ---- small tables ----
    if (tid < H_) watt[tid] = w_att[tid];
    {
        int idx = b0 * N_ + tid;           // MB*N_ == 512 == blockDim
        rids[tid >> 5][tid & 31] = rel_ids[idx];
        bool vm = m8flag ? (((const unsigned char*)vmaskp)[idx] != 0)
                         : (((const int*)vmaskp)[idx] != 0);
        dall[tid >> 5][tid & 31] = vm ? DECAY : 1.0f;
    }
    for (int i = tid; i < R_ * H_; i += 512) ((float*)bfl)[i] = b_f[i];
    if (tid == 0) rdotL[3] = b_att[0];
    __syncthreads();

    // rdot[r] = dot(rel_emb[r], w_att); published by chunk-0's barriers
    if (wave < R_) {
        int r = wave;
        float p = 0.f;
        #pragma unroll
        for (int j = 0; j < 4; ++j) {
            int h = lane * 4 + j;
            p += rel_emb[r * H_ + h] * watt[h];
        }
        #pragma unroll
        for (int off = 32; off >= 1; off >>= 1) p += __shfl_xor(p, off);
        if (lane == 0) rdotL[r] = p;
    }

    // ================= chunk loop: NBC=4 batches each =================
    for (int ck = 0; ck < CHUNKS; ++ck) {
        __syncthreads();     // chs/scoreT free (prev chunk's reads done)

        // ---- stage child_h (nt fp32 -> bf16 LDS) with FUSED attention dot ----
        // 8 its x 512 thr x 8 elems = 4 batches x 32 rows x 256.
        {
            size_t base = (size_t)(b0 + ck * NBC) * (N_ * H_);
            float dp[8];
            #pragma unroll
            for (int it = 0; it < 8; ++it) {
                int ge = (it * 512 + tid) << 3;          // 0..32760
                int row = ge >> 8;                       // 0..127 (= bi*32+n)
                int h = ge & 255;
                f32x4 a = __builtin_nontemporal_load((const f32x4*)(child_h + base + ge));
                f32x4 b = __builtin_nontemporal_load((const f32x4*)(child_h + base + ge + 4));
                bf16x8 r; float p = 0.f;
                #pragma unroll
                for (int j = 0; j < 4; ++j) {
                    r[j] = (bf16)a[j]; r[j + 4] = (bf16)b[j];
                    p += a[j] * watt[h + j] + b[j] * watt[h + 4 + j];
                }
                *(bf16x8*)(&chs[row >> 5][row & 31][h]) = r;
                dp[it] = p;
            }
            #pragma unroll
            for (int off = 16; off >= 1; off >>= 1) {
                #pragma unroll
                for (int it = 0; it < 8; ++it) dp[it] += __shfl_xor(dp[it], off);
            }
            if ((tid & 31) == 0) {
                int grp = tid >> 5;                      // 0..15
                #pragma unroll
                for (int it = 0; it < 8; ++it) scoreT[it * 16 + grp] = dp[it];
            }
        }
        __syncthreads();

        // ---- per-wave softmax: 128 (bi,n) pairs, 2 per lane, in regs ----
        float att0, att1;   // att*decay for (bi=lane>>5, n) and (bi=2+lane>>5, n)
        {
            int n  = lane & 31;
            int bi = lane >> 5;
            int bl0 = ck * NBC + bi, bl1 = bl0 + 2;
            float d0 = dall[bl0][n], d1 = dall[bl1][n];
            float s0 = d0 * scoreT[lane]      + rdotL[rids[bl0][n]] + rdotL[3];
            float s1 = d1 * scoreT[64 + lane] + rdotL[rids[bl1][n]] + rdotL[3];
            float m0 = s0, m1 = s1;
            #pragma unroll
            for (int off = 16; off >= 1; off >>= 1) {
                m0 = fmaxf(m0, __shfl_xor(m0, off));
                m1 = fmaxf(m1, __shfl_xor(m1, off));
            }
            float e0 = __expf(s0 - m0), e1 = __expf(s1 - m1);
            float u0 = e0, u1 = e1;
            #pragma unroll
            for (int off = 16; off >= 1; off >>= 1) {
                u0 += __shfl_xor(u0, off);
                u1 += __shfl_xor(u1, off);
            }
            att0 = (e0 / u0) * d0;
            att1 = (e1 / u1) * d1;
        }

        // ---- h_sum -> LDS (2 passes; attn via shfl broadcast) ----
        #pragma unroll
        for (int ps = 0; ps < 2; ++ps) {
            int bi = (tid >> 8) + ps * 2;
            int g  = tid & 255;
            int bl = ck * NBC + bi;
            float s = 0.f;
            #pragma unroll 8
            for (int n = 0; n < N_; ++n) {
                float av = __shfl(ps ? att1 : att0, ((tid >> 8) << 5) | n);
                s += av * (float)chs[bi][n][g];
            }
            hsumL[bl][g] = (bf16)s;
        }

        // ---- rid-masked MFMA GEMM: Q[g,n] (M=256, N=128, K=3x256) ----
        f32x4 acc[2][8];
        #pragma unroll
        for (int i = 0; i < 2; ++i)
            #pragma unroll
            for (int j = 0; j < 8; ++j)
                #pragma unroll
                for (int c = 0; c < 4; ++c) acc[i][j][c] = 0.0f;

        bf16x8 bzero;
        #pragma unroll
        for (int i = 0; i < 8; ++i) bzero[i] = (bf16)0.0f;

        int myrid[8];
        #pragma unroll
        for (int nt = 0; nt < 8; ++nt)
            myrid[nt] = rids[ck * NBC + (nt >> 1)][((nt & 1) << 4) + t];

        #pragma unroll
        for (int kc = 0; kc < 8; ++kc) {
            const int k = kc * 32 + q * 8;
            bf16x8 v[8];
            #pragma unroll
            for (int nt = 0; nt < 8; ++nt)
                v[nt] = *(const bf16x8*)(&chs[nt >> 1][((nt & 1) << 4) + t][k]);
            #pragma unroll
            for (int r = 0; r < R_; ++r) {
                bf16x8 afrag[2];
                #pragma unroll
                for (int m2 = 0; m2 < 2; ++m2) {
                    int g = (wave * 2 + m2) * 16 + t;
                    afrag[m2] = ldw8<WSW>(wfb, W_f, (r * H_ + g) * H_ + k);
                }
                #pragma unroll
                for (int nt = 0; nt < 8; ++nt) {
                    bf16x8 vm = (myrid[nt] == r) ? v[nt] : bzero;
                    acc[0][nt] = __builtin_amdgcn_mfma_f32_16x16x32_bf16(afrag[0], vm, acc[0][nt], 0, 0, 0);
                    acc[1][nt] = __builtin_amdgcn_mfma_f32_16x16x32_bf16(afrag[1], vm, acc[1][nt], 0, 0, 0);
                }
            }
        }

        // ---- cs epilogue: direct child_c global loads (no LDS stage/barrier) ----
        // cs[bl][g] = sum_n cc*d*(d*Q + b_f[rid]); 4-lane q-groups cover 64 B rows.
        {
            f32x4 cc[2][4][2];   // [m2][bi][j]
            #pragma unroll
            for (int m2 = 0; m2 < 2; ++m2)
                #pragma unroll
                for (int bi = 0; bi < NBC; ++bi) {
                    size_t cbase = (size_t)(b0 + ck * NBC + bi) * (N_ * H_);
                    #pragma unroll
                    for (int j = 0; j < 2; ++j)
                        cc[m2][bi][j] = __builtin_nontemporal_load(
                            (const f32x4*)(child_c + cbase + (size_t)(((j << 4) + t)) * H_
                                           + (wave * 2 + m2) * 16 + q * 4));
                }
            #pragma unroll
            for (int m2 = 0; m2 < 2; ++m2) {
                #pragma unroll
                for (int reg = 0; reg < 4; ++reg) {
                    const int g = (wave * 2 + m2) * 16 + q * 4 + reg;
                    #pragma unroll
                    for (int bi = 0; bi < NBC; ++bi) {
                        int bl = ck * NBC + bi;
                        float p = 0.f;
                        #pragma unroll
                        for (int j = 0; j < 2; ++j) {
                            int nt = bi * 2 + j;
                            int n  = (j << 4) + t;
                            float d = dall[bl][n];
                            p += cc[m2][bi][j][reg] * d
                                 * fmaf(d, acc[m2][nt][reg], bfl[rids[bl][n]][g]);
                        }
                        p += __shfl_xor(p, 1);
                        p += __shfl_xor(p, 2);
                        p += __shfl_xor(p, 4);
                        p += __shfl_xor(p, 8);
                        if (t == 0) csL[bl][g] = p;
                    }
                }
            }
        }
    }
    __syncthreads();

    // ============ gates: (16 x 512) @ (512 x 768), fused epilogue ============
    const int j0 = wave * 32;
    f32x4 accI[2], accO[2], accU[2];
    #pragma unroll
    for (int c = 0; c < 2; ++c)
        #pragma unroll
        for (int r = 0; r < 4; ++r) { accI[c][r] = 0.f; accO[c][r] = 0.f; accU[c][r] = 0.f; }

    #pragma unroll
    for (int kc = 0; kc < 16; ++kc) {
        const int k = kc * 32 + q * 8;
        bf16x8 a;
        if (kc < 8) a = cvt8_nt(ivec + (size_t)(b0 + t) * DIN_ + k);
        else        a = *(const bf16x8*)(&hsumL[t][k - 256]);
        #pragma unroll
        for (int c = 0; c < 2; ++c) {
            int j = j0 + c * 16 + t;
            bf16x8 bI = ldw8<WSW>(wib, W_i, j * 512 + k);
            bf16x8 bO = ldw8<WSW>(wob, W_o, j * 512 + k);
            bf16x8 bU = ldw8<WSW>(wub, W_u, j * 512 + k);
            accI[c] = __builtin_amdgcn_mfma_f32_16x16x32_bf16(a, bI, accI[c], 0, 0, 0);
            accO[c] = __builtin_amdgcn_mfma_f32_16x16x32_bf16(a, bO, accO[c], 0, 0, 0);
            accU[c] = __builtin_amdgcn_mfma_f32_16x16x32_bf16(a, bU, accU[c], 0, 0, 0);
        }
    }

    #pragma unroll
    for (int c = 0; c < 2; ++c) {
        const int j = j0 + c * 16 + t;
        float biv = b_i[j], bov = b_o[j], buv = b_u[j];
        #pragma unroll
        for (int reg = 0; reg < 4; ++reg) {
            int bl = q * 4 + reg;
            size_t o1 = (size_t)(b0 + bl) * H_ + j;
            size_t o2 = (size_t)B_ * H_ + o1;
            float iv = sigmoidf_(accI[c][reg] + biv);
            float ov = sigmoidf_(accO[c][reg] + bov);
            float uv = tanhf(accU[c][reg] + buv);
            float cv = fmaf(iv, uv, csL[bl][j]);
            float hv = ov * tanhf(cv);
            __builtin_nontemporal_store(hv, out + o1);
            __builtin_nontemporal_store(cv, out + o2);
        }
    }
}

extern "C" void kernel_launch(void* const* d_in, const int* in_sizes, int n_in,
                              void* d_out, int out_size, void* d_ws, size_t ws_size,
                              hipStream_t stream)
{
    const float* ivec    = (const float*)d_in[0];
    const float* child_h = (const float*)d_in[1];
    const float* child_c = (const float*)d_in[2];
    const int*   relids  = (const int*)d_in[3];
    const void*  vmask   = d_in[4];
    const float* rel_emb = (const float*)d_in[5];
    const float* W_i     = (const float*)d_in[6];
    const float* b_i     = (const float*)d_in[7];
    const float* W_f     = (const float*)d_in[8];
    const float* b_f     = (const float*)d_in[9];
    const float* W_o     = (const float*)d_in[10];
    const float* b_o     = (const float*)d_in[11];
    const float* W_u     = (const float*)d_in[12];
    const float* b_u     = (const float*)d_in[13];
    const float* w_att   = (const float*)d_in[14];
    const float* b_att   = (const float*)d_in[15];
    float* out = (float*)d_out;
    bf16*  ws  = (bf16*)d_ws;

    const bool wsw = (ws_size >= (size_t)WS_ELEMS * sizeof(bf16));

    if (wsw) {
        hipLaunchKernelGGL(wprep, dim3(WS_ELEMS / 8 / 256), dim3(256), 0, stream,
                           W_f, W_i, W_o, W_u, ws);
        hipLaunchKernelGGL((fused_main<true>), dim3(B_ / MB), dim3(512), 0, stream,
                           ivec, child_h, child_c, relids, vmask, rel_emb,
                           W_i, b_i, W_f, b_f, W_o, b_o, W_u, b_u, w_att, b_att,
                           ws, out);
    } else {
        hipLaunchKernelGGL((fused_main<false>), dim3(B_ / MB), dim3(512), 0, stream,
                           ivec, child_h, child_c, relids, vmask, rel_emb,
                           W_i, b_i, W_f, b_f, W_o, b_o, W_u, b_u, w_att, b_att,
                           ws, out);
    }
}

// Round 8
// 422.622 us; speedup vs baseline: 1.1029x; 1.0054x over previous
//
#include <hip/hip_runtime.h>
#include <hip/hip_bf16.h>
#include <math.h>

// RelationAwareTreeLSTMCell on gfx950 — fp32 in/out.
// B=4096 N=32 H=256 DIN=256 R=3.
// Round 11: ride the confirmed pass-count slope (dur ~ linear in B/NBC W_f
//   streaming passes: 2048->242-256us, 1024->201us). NBC=8 -> 512 passes.
//   To fit chs[8][32][264] (135 KB): csL leaves LDS — cs epilogue stores
//   partial c to out[B+b][h] (plain store), gate epilogue reads it back after
//   __syncthreads (same CU, vmcnt drained at barrier, L2-coherent) and
//   overwrites with final c. LDS ~149 KB, 1 block/CU, grid 256 (1 round,
//   gate passes unchanged vs r10). GEMM nt=16, acc[2][16] (AGPR-resident
//   under waves_per_eu(2,2) 256-reg budget); cs epilogue in 4 bi-pair groups.
// fused_main: 256 blocks x 512 thr, 2 chunks of NBC=8 batches.
//   Per chunk: barrier -> stage child_h (fused attn dot, 16 its) -> barrier ->
//   per-wave softmax (4 pairs/lane) -> hsum (4 passes) ->
//   rid-masked MFMA GEMM (M=256,N=256,K=3x256) -> direct-cc cs epilogue -> out.
//   Then gate GEMM (16 x 512)@(512 x 768) + fused sigmoid/tanh -> fp32 out.

#define B_    4096
#define N_    32
#define H_    256
#define DIN_  256
#define R_    3
#define MB    16
#define NBC   8
#define CHUNKS (MB / NBC)
#define DECAY 0.7f

// ws layout (bf16 elements)
#define WS_WF   0
#define WS_WI   196608
#define WS_WO   327680
#define WS_WU   458752
#define WS_ELEMS 589824                       // * 2 B = 1,179,648 B needed

typedef __bf16 bf16;
typedef bf16  bf16x8 __attribute__((ext_vector_type(8)));
typedef float f32x4  __attribute__((ext_vector_type(4)));

__device__ __forceinline__ float sigmoidf_(float x) { return 1.0f / (1.0f + __expf(-x)); }

__device__ __forceinline__ bf16x8 cvt8_nt(const float* p) {
    f32x4 a = __builtin_nontemporal_load((const f32x4*)p);
    f32x4 b = __builtin_nontemporal_load((const f32x4*)(p + 4));
    bf16x8 r;
    #pragma unroll
    for (int j = 0; j < 4; ++j) { r[j] = (bf16)a[j]; r[j + 4] = (bf16)b[j]; }
    return r;
}
__device__ __forceinline__ bf16x8 cvt8_c(const float* p) {
    f32x4 a = *(const f32x4*)p;
    f32x4 b = *(const f32x4*)(p + 4);
    bf16x8 r;
    #pragma unroll
    for (int j = 0; j < 4; ++j) { r[j] = (bf16)a[j]; r[j + 4] = (bf16)b[j]; }
    return r;
}

template<bool WSW>
__device__ __forceinline__ bf16x8 ldw8(const bf16* wsp, const float* fp, int idx) {
    if constexpr (WSW) return *(const bf16x8*)(wsp + idx);
    else               return cvt8_c(fp + idx);
}

// ---- weight prep: fp32 -> bf16 into d_ws. 288 blocks x 256 thr, exact cover. ----
__global__ __launch_bounds__(256) void wprep(
    const float* __restrict__ Wf, const float* __restrict__ Wi,
    const float* __restrict__ Wo, const float* __restrict__ Wu,
    bf16* __restrict__ ws)
{
    int i = (blockIdx.x * 256 + threadIdx.x) * 8;
    const float* src; int off;
    if      (i < WS_WI) { src = Wf; off = i - WS_WF; }
    else if (i < WS_WO) { src = Wi; off = i - WS_WI; }
    else if (i < WS_WU) { src = Wo; off = i - WS_WO; }
    else                { src = Wu; off = i - WS_WU; }
    *(bf16x8*)(ws + i) = cvt8_c(src + off);
}

template<bool WSW>
__global__ __launch_bounds__(512) __attribute__((amdgpu_waves_per_eu(2, 2)))
void fused_main(
    const float* __restrict__ ivec,
    const float* __restrict__ child_h, const float* __restrict__ child_c,
    const int*  __restrict__ rel_ids,  const void* __restrict__ vmaskp,
    const float* __restrict__ rel_emb,
    const float* __restrict__ W_i, const float* __restrict__ b_i,
    const float* __restrict__ W_f, const float* __restrict__ b_f,
    const float* __restrict__ W_o, const float* __restrict__ b_o,
    const float* __restrict__ W_u, const float* __restrict__ b_u,
    const float* __restrict__ w_att, const float* __restrict__ b_att,
    const bf16* __restrict__ ws, float* __restrict__ out)
{
    __shared__ __align__(16) bf16 chs[NBC][N_][264];   // 135168 B
    __shared__ __align__(16) bf16 hsumL[MB][264];      //   8448 B
    __shared__ float watt[H_];                         //   1024 B
    __shared__ float bfl[R_][H_];                      //   3072 B
    __shared__ float dall[MB][N_];                     //   2048 B
    __shared__ int   rids[MB][N_];                     //   2048 B
    __shared__ float scoreT[NBC * N_];                 //   1024 B
    __shared__ float rdotL[4];
    __shared__ int   m8flag;
    // total ~149.3 KB

    const int tid  = threadIdx.x;
    const int wave = tid >> 6;
    const int lane = tid & 63;
    const int t    = lane & 15;
    const int q    = lane >> 4;
    const int b0   = blockIdx.x * MB;

    const bf16* wfb = ws + WS_WF;
    const bf16* wib = ws + WS_WI;
    const bf16* wob = ws + WS_WO;
    const bf16* wub = ws + WS_WU;

    // ---- mask-format probe (wave 0): byte-bools have nonzero "upper bytes" ----
    if (tid < 64) {
        const unsigned char* vb = (const unsigned char*)vmaskp;
        int bad = vb[tid * 4 + 1] | vb[tid * 4 + 2] | vb[tid * 4 + 3];
        unsigned long long any = __ballot(bad != 0);
        if (tid == 0) m8flag = (any != 0ull) ? 1 : 0;
    }
    __syncthreads();

    // ---- small tables ----
    if (tid < H_) watt[tid] = w_att[tid];
    {
        int idx = b0 * N_ + tid;           // MB*N_ == 512 == blockDim
        rids[tid >> 5][tid & 31] = rel_ids[idx];
        bool vm = m8flag ? (((const unsigned char*)vmaskp)[idx] != 0)
                         : (((const int*)vmaskp)[idx] != 0);
        dall[tid >> 5][tid & 31] = vm ? DECAY : 1.0f;
    }
    for (int i = tid; i < R_ * H_; i += 512) ((float*)bfl)[i] = b_f[i];
    if (tid == 0) rdotL[3] = b_att[0];
    __syncthreads();

    // rdot[r] = dot(rel_emb[r], w_att); published by chunk-0's barriers
    if (wave < R_) {
        int r = wave;
        float p = 0.f;
        #pragma unroll
        for (int j = 0; j < 4; ++j) {
            int h = lane * 4 + j;
            p += rel_emb[r * H_ + h] * watt[h];
        }
        #pragma unroll
        for (int off = 32; off >= 1; off >>= 1) p += __shfl_xor(p, off);
        if (lane == 0) rdotL[r] = p;
    }

    // ================= chunk loop: NBC=8 batches each =================
    for (int ck = 0; ck < CHUNKS; ++ck) {
        __syncthreads();     // chs/scoreT free (prev chunk's reads done)

        // ---- stage child_h (nt fp32 -> bf16 LDS) with FUSED attention dot ----
        // 16 its x 512 thr x 8 elems = 8 batches x 32 rows x 256.
        {
            size_t base = (size_t)(b0 + ck * NBC) * (N_ * H_);
            float dp[16];
            #pragma unroll
            for (int it = 0; it < 16; ++it) {
                int ge = (it * 512 + tid) << 3;          // 0..65528
                int row = ge >> 8;                       // 0..255 (= bi*32+n)
                int h = ge & 255;
                f32x4 a = __builtin_nontemporal_load((const f32x4*)(child_h + base + ge));
                f32x4 b = __builtin_nontemporal_load((const f32x4*)(child_h + base + ge + 4));
                bf16x8 r; float p = 0.f;
                #pragma unroll
                for (int j = 0; j < 4; ++j) {
                    r[j] = (bf16)a[j]; r[j + 4] = (bf16)b[j];
                    p += a[j] * watt[h + j] + b[j] * watt[h + 4 + j];
                }
                *(bf16x8*)(&chs[row >> 5][row & 31][h]) = r;
                dp[it] = p;
            }
            #pragma unroll
            for (int off = 16; off >= 1; off >>= 1) {
                #pragma unroll
                for (int it = 0; it < 16; ++it) dp[it] += __shfl_xor(dp[it], off);
            }
            if ((tid & 31) == 0) {
                int grp = tid >> 5;                      // 0..15
                #pragma unroll
                for (int it = 0; it < 16; ++it) scoreT[it * 16 + grp] = dp[it];
            }
        }
        __syncthreads();

        // ---- per-wave softmax: 256 (bi,n) pairs, 4 per lane, in regs ----
        // lane holds (bi = 2k + hb, n = lane&31), hb = lane>>5, k = 0..3.
        float att[4];
        {
            int n  = lane & 31;
            int hb = lane >> 5;
            #pragma unroll
            for (int k = 0; k < 4; ++k) {
                int bi = 2 * k + hb;
                int bl = ck * NBC + bi;
                float d = dall[bl][n];
                float s = d * scoreT[64 * k + lane] + rdotL[rids[bl][n]] + rdotL[3];
                float m = s;
                #pragma unroll
                for (int off = 16; off >= 1; off >>= 1) m = fmaxf(m, __shfl_xor(m, off));
                float e = __expf(s - m);
                float sum = e;
                #pragma unroll
                for (int off = 16; off >= 1; off >>= 1) sum += __shfl_xor(sum, off);
                att[k] = (e / sum) * d;
            }
        }

        // ---- h_sum -> LDS (4 passes; attn via shfl broadcast) ----
        #pragma unroll
        for (int ps = 0; ps < 4; ++ps) {
            int hb = tid >> 8;                 // 0..1
            int bi = 2 * ps + hb;
            int g  = tid & 255;
            int bl = ck * NBC + bi;
            float s = 0.f;
            #pragma unroll 8
            for (int n = 0; n < N_; ++n) {
                float av = __shfl(att[ps], n + (hb << 5));
                s += av * (float)chs[bi][n][g];
            }
            hsumL[bl][g] = (bf16)s;
        }

        // ---- rid-masked MFMA GEMM: Q[g,n] (M=256, N=256, K=3x256) ----
        f32x4 acc[2][16];
        #pragma unroll
        for (int i = 0; i < 2; ++i)
            #pragma unroll
            for (int j = 0; j < 16; ++j)
                #pragma unroll
                for (int c = 0; c < 4; ++c) acc[i][j][c] = 0.0f;

        bf16x8 bzero;
        #pragma unroll
        for (int i = 0; i < 8; ++i) bzero[i] = (bf16)0.0f;

        int myrid[16];
        #pragma unroll
        for (int nt = 0; nt < 16; ++nt)
            myrid[nt] = rids[ck * NBC + (nt >> 1)][((nt & 1) << 4) + t];

        #pragma unroll
        for (int kc = 0; kc < 8; ++kc) {
            const int k = kc * 32 + q * 8;
            bf16x8 v[16];
            #pragma unroll
            for (int nt = 0; nt < 16; ++nt)
                v[nt] = *(const bf16x8*)(&chs[nt >> 1][((nt & 1) << 4) + t][k]);
            #pragma unroll
            for (int r = 0; r < R_; ++r) {
                bf16x8 afrag[2];
                #pragma unroll
                for (int m2 = 0; m2 < 2; ++m2) {
                    int g = (wave * 2 + m2) * 16 + t;
                    afrag[m2] = ldw8<WSW>(wfb, W_f, (r * H_ + g) * H_ + k);
                }
                #pragma unroll
                for (int nt = 0; nt < 16; ++nt) {
                    bf16x8 vm = (myrid[nt] == r) ? v[nt] : bzero;
                    acc[0][nt] = __builtin_amdgcn_mfma_f32_16x16x32_bf16(afrag[0], vm, acc[0][nt], 0, 0, 0);
                    acc[1][nt] = __builtin_amdgcn_mfma_f32_16x16x32_bf16(afrag[1], vm, acc[1][nt], 0, 0, 0);
                }
            }
        }

        // ---- cs epilogue: direct child_c loads, 4 bi-pair groups; cs -> out ----
        // cs[bl][g] = sum_n cc*d*(d*Q + b_f[rid]); partial c stored to out[B+b].
        #pragma unroll
        for (int bg = 0; bg < 4; ++bg) {
            f32x4 cc[2][2][2];   // [m2][bp][j], bi = bg*2+bp
            #pragma unroll
            for (int m2 = 0; m2 < 2; ++m2)
                #pragma unroll
                for (int bp = 0; bp < 2; ++bp) {
                    int bi = bg * 2 + bp;
                    size_t cbase = (size_t)(b0 + ck * NBC + bi) * (N_ * H_);
                    #pragma unroll
                    for (int j = 0; j < 2; ++j)
                        cc[m2][bp][j] = __builtin_nontemporal_load(
                            (const f32x4*)(child_c + cbase + (size_t)(((j << 4) + t)) * H_
                                           + (wave * 2 + m2) * 16 + q * 4));
                }
            #pragma unroll
            for (int m2 = 0; m2 < 2; ++m2) {
                #pragma unroll
                for (int reg = 0; reg < 4; ++reg) {
                    const int g = (wave * 2 + m2) * 16 + q * 4 + reg;
                    #pragma unroll
                    for (int bp = 0; bp < 2; ++bp) {
                        int bi = bg * 2 + bp;
                        int bl = ck * NBC + bi;
                        float p = 0.f;
                        #pragma unroll
                        for (int j = 0; j < 2; ++j) {
                            int nt = bi * 2 + j;
                            int n  = (j << 4) + t;
                            float d = dall[bl][n];
                            p += cc[m2][bp][j][reg] * d
                                 * fmaf(d, acc[m2][nt][reg], bfl[rids[bl][n]][g]);
                        }
                        p += __shfl_xor(p, 1);
                        p += __shfl_xor(p, 2);
                        p += __shfl_xor(p, 4);
                        p += __shfl_xor(p, 8);
                        if (t == 0)
                            out[(size_t)B_ * H_ + (size_t)(b0 + bl) * H_ + g] = p;
                    }
                }
            }
        }
    }
    __syncthreads();   // drains vmcnt before barrier: cs stores visible block-wide

    // ============ gates: (16 x 512) @ (512 x 768), fused epilogue ============
    const int j0 = wave * 32;
    f32x4 accI[2], accO[2], accU[2];
    #pragma unroll
    for (int c = 0; c < 2; ++c)
        #pragma unroll
        for (int r = 0; r < 4; ++r) { accI[c][r] = 0.f; accO[c][r] = 0.f; accU[c][r] = 0.f; }

    #pragma unroll
    for (int kc = 0; kc < 16; ++kc) {
        const int k = kc * 32 + q * 8;
        bf16x8 a;
        if (kc < 8) a = cvt8_nt(ivec + (size_t)(b0 + t) * DIN_ + k);
        else        a = *(const bf16x8*)(&hsumL[t][k - 256]);
        #pragma unroll
        for (int c = 0; c < 2; ++c) {
            int j = j0 + c * 16 + t;
            bf16x8 bI = ldw8<WSW>(wib, W_i, j * 512 + k);
            bf16x8 bO = ldw8<WSW>(wob, W_o, j * 512 + k);
            bf16x8 bU = ldw8<WSW>(wub, W_u, j * 512 + k);
            accI[c] = __builtin_amdgcn_mfma_f32_16x16x32_bf16(a, bI, accI[c], 0, 0, 0);
            accO[c] = __builtin_amdgcn_mfma_f32_16x16x32_bf16(a, bO, accO[c], 0, 0, 0);
            accU[c] = __builtin_amdgcn_mfma_f32_16x16x32_bf16(a, bU, accU[c], 0, 0, 0);
        }
    }

    #pragma unroll
    for (int c = 0; c < 2; ++c) {
        const int j = j0 + c * 16 + t;
        float biv = b_i[j], bov = b_o[j], buv = b_u[j];
        #pragma unroll
        for (int reg = 0; reg < 4; ++reg) {
            int bl = q * 4 + reg;
            size_t o1 = (size_t)(b0 + bl) * H_ + j;
            size_t o2 = (size_t)B_ * H_ + o1;
            float csv = out[o2];                       // partial c from cs epilogue
            float iv = sigmoidf_(accI[c][reg] + biv);
            float ov = sigmoidf_(accO[c][reg] + bov);
            float uv = tanhf(accU[c][reg] + buv);
            float cv = fmaf(iv, uv, csv);
            float hv = ov * tanhf(cv);
            __builtin_nontemporal_store(hv, out + o1);
            __builtin_nontemporal_store(cv, out + o2);
        }
    }
}

extern "C" void kernel_launch(void* const* d_in, const int* in_sizes, int n_in,
                              void* d_out, int out_size, void* d_ws, size_t ws_size,
                              hipStream_t stream)
{
    const float* ivec    = (const float*)d_in[0];
    const float* child_h = (const float*)d_in[1];
    const float* child_c = (const float*)d_in[2];
    const int*   relids  = (const int*)d_in[3];
    const void*  vmask   = d_in[4];
    const float* rel_emb = (const float*)d_in[5];
    const float* W_i     = (const float*)d_in[6];
    const float* b_i     = (const float*)d_in[7];
    const float* W_f     = (const float*)d_in[8];
    const float* b_f     = (const float*)d_in[9];
    const float* W_o     = (const float*)d_in[10];
    const float* b_o     = (const float*)d_in[11];
    const float* W_u     = (const float*)d_in[12];
    const float* b_u     = (const float*)d_in[13];
    const float* w_att   = (const float*)d_in[14];
    const float* b_att   = (const float*)d_in[15];
    float* out = (float*)d_out;
    bf16*  ws  = (bf16*)d_ws;

    const bool wsw = (ws_size >= (size_t)WS_ELEMS * sizeof(bf16));

    if (wsw) {
        hipLaunchKernelGGL(wprep, dim3(WS_ELEMS / 8 / 256), dim3(256), 0, stream,
                           W_f, W_i, W_o, W_u, ws);
        hipLaunchKernelGGL((fused_main<true>), dim3(B_ / MB), dim3(512), 0, stream,
                           ivec, child_h, child_c, relids, vmask, rel_emb,
                           W_i, b_i, W_f, b_f, W_o, b_o, W_u, b_u, w_att, b_att,
                           ws, out);
    } else {
        hipLaunchKernelGGL((fused_main<false>), dim3(B_ / MB), dim3(512), 0, stream,
                           ivec, child_h, child_c, relids, vmask, rel_emb,
                           W_i, b_i, W_f, b_f, W_o, b_o, W_u, b_u, w_att, b_att,
                           ws, out);
    }
}